// Round 1
// baseline (710.061 us; speedup 1.0000x reference)
//
#include <hip/hip_runtime.h>
#include <hip/hip_bf16.h>
#include <math.h>

typedef __bf16 bf16_t;
typedef __bf16 bf16x8 __attribute__((ext_vector_type(8)));
typedef __bf16 bf16x4 __attribute__((ext_vector_type(4)));
typedef float f32x4 __attribute__((ext_vector_type(4)));

#define MFMA16x16x32 __builtin_amdgcn_mfma_f32_16x16x32_bf16

// ---------------- x: f32 -> bf16 ----------------
__global__ void k_f32_to_bf16(const float* __restrict__ in, bf16_t* __restrict__ out, long n) {
  long i = ((long)blockIdx.x * blockDim.x + threadIdx.x) * 4;
  long stride = (long)gridDim.x * blockDim.x * 4;
  for (; i < n; i += stride) {
    const float4 v = *(const float4*)(in + i);
    bf16x4 o; o[0] = (bf16_t)v.x; o[1] = (bf16_t)v.y; o[2] = (bf16_t)v.z; o[3] = (bf16_t)v.w;
    *(bf16x4*)(out + i) = o;
  }
}

// ------------- W (KxN f32) -> WT (NxK bf16), LDS tile transpose -------------
__global__ void k_transpose_bf16(const float* __restrict__ W, bf16_t* __restrict__ WT,
                                 int K, int N) {
  __shared__ float tile[32][33];
  int n0 = blockIdx.x * 32, k0 = blockIdx.y * 32;
  int tx = threadIdx.x & 31, ty = threadIdx.x >> 5;
#pragma unroll
  for (int i = 0; i < 4; i++)
    tile[ty + i * 8][tx] = W[(size_t)(k0 + ty + i * 8) * N + n0 + tx];
  __syncthreads();
#pragma unroll
  for (int i = 0; i < 4; i++) {
    int n = ty + i * 8;
    WT[(size_t)(n0 + n) * K + k0 + tx] = (bf16_t)tile[tx][n];
  }
}

// ---------------- RoPE on q,k columns of qkv (in place) ----------------
// qkv: [8192][3072] bf16. pairs p in [0,1280): cols (2p,2p+1) < 2560.
__global__ void k_rope(bf16_t* __restrict__ qkv) {
  int idx = blockIdx.x * blockDim.x + threadIdx.x;
  if (idx >= 8192 * 1280) return;
  int r = idx / 1280, p = idx - r * 1280;
  int t = r & 2047;
  int i = p & 63;
  // theta_i = 10000^(-i/32) = exp2(-i * log2(10000)/32)
  float theta = exp2f(-(float)i * 0.41524101186092029f);
  float f = (float)t * theta;
  float s, c;
  sincosf(f, &s, &c);
  bf16_t* a = qkv + (size_t)r * 3072 + p * 2;
  float e = (float)a[0], o = (float)a[1];
  a[0] = (bf16_t)(e * c - o * s);
  a[1] = (bf16_t)(e * s + o * c);
}

// ---------------- GEMM: C[MxN] = A[MxK] * BT[NxK]^T (+bias) ----------------
// 128x128 tile, BK=64, 4 waves (2x2 of 64x64), mfma 16x16x32 bf16.
template <bool F32OUT>
__global__ __launch_bounds__(256, 2) void k_gemm_bt(
    const bf16_t* __restrict__ A, const bf16_t* __restrict__ BT,
    bf16_t* __restrict__ Cb, float* __restrict__ Cf,
    const float* __restrict__ bias, int M, int N, int K) {
  const int LDK = 72;  // 64 + 8 pad: row stride 144B (16B-aligned, conflict-light)
  __shared__ bf16_t sA[128 * 72];
  __shared__ bf16_t sB[128 * 72];
  int nbn = N >> 7;
  int bm = (int)blockIdx.x / nbn, bn = (int)blockIdx.x % nbn;
  int tid = threadIdx.x;
  int lane = tid & 63, wid = tid >> 6;
  int wm = (wid >> 1) << 6, wn = (wid & 1) << 6;
  int lr = lane & 15, lq = lane >> 4;
  f32x4 acc[4][4] = {};
  int srow = tid >> 3, scol = (tid & 7) * 8;
  const bf16_t* Ab = A + (size_t)(bm * 128 + srow) * K + scol;
  const bf16_t* Bb = BT + (size_t)(bn * 128 + srow) * K + scol;

  for (int k0 = 0; k0 < K; k0 += 64) {
#pragma unroll
    for (int i = 0; i < 4; i++) {
      *(bf16x8*)&sA[(srow + i * 32) * LDK + scol] = *(const bf16x8*)(Ab + (size_t)i * 32 * K + k0);
      *(bf16x8*)&sB[(srow + i * 32) * LDK + scol] = *(const bf16x8*)(Bb + (size_t)i * 32 * K + k0);
    }
    __syncthreads();
#pragma unroll
    for (int kc = 0; kc < 2; kc++) {
      bf16x8 af[4], bfr[4];
#pragma unroll
      for (int m = 0; m < 4; m++)
        af[m] = *(const bf16x8*)&sA[(wm + m * 16 + lr) * LDK + kc * 32 + lq * 8];
#pragma unroll
      for (int n = 0; n < 4; n++)
        bfr[n] = *(const bf16x8*)&sB[(wn + n * 16 + lr) * LDK + kc * 32 + lq * 8];
#pragma unroll
      for (int m = 0; m < 4; m++)
#pragma unroll
        for (int n = 0; n < 4; n++)
          acc[m][n] = MFMA16x16x32(af[m], bfr[n], acc[m][n], 0, 0, 0);
    }
    __syncthreads();
  }
  // epilogue: C layout col=lane&15, row=(lane>>4)*4+reg
#pragma unroll
  for (int m = 0; m < 4; m++) {
    int row0 = bm * 128 + wm + m * 16 + lq * 4;
#pragma unroll
    for (int n = 0; n < 4; n++) {
      int col = bn * 128 + wn + n * 16 + lr;
#pragma unroll
      for (int r = 0; r < 4; r++) {
        if constexpr (F32OUT)
          Cf[(size_t)(row0 + r) * N + col] = acc[m][n][r] + bias[col];
        else
          Cb[(size_t)(row0 + r) * N + col] = (bf16_t)acc[m][n][r];
      }
    }
  }
}

// ---------------- Flash attention (causal, GQA) ----------------
// grid (32, 16, 4) = (q-tile, head, batch); 256 thr = 4 waves x 16 q-rows.
__global__ __launch_bounds__(256, 2) void k_attn(const bf16_t* __restrict__ qkv,
                                                 bf16_t* __restrict__ out) {
  const int LDKs = 136, LDV = 72, LDP = 72;
  __shared__ bf16_t sK[64 * 136];   // K tile row-major [64][128]+pad
  __shared__ bf16_t sVT[128 * 72];  // V tile transposed [128][64]+pad
  __shared__ bf16_t sP[4][16 * 72]; // per-wave P [16][64]+pad
  int qt = blockIdx.x, h = blockIdx.y, b = blockIdx.z;
  int kvh = h >> 2;
  const size_t RS = 3072;
  const bf16_t* Qb = qkv + (size_t)b * 2048 * RS + h * 128;
  const bf16_t* Kb = qkv + (size_t)b * 2048 * RS + 2048 + kvh * 128;
  const bf16_t* Vb = Kb + 512;  // = 2560 + kvh*128
  int q0 = qt * 64;
  int tid = threadIdx.x, lane = tid & 63, wid = tid >> 6;
  int lr = lane & 15, lq = lane >> 4;
  int qw = q0 + wid * 16;

  // Q fragments in registers (A operand: row=lane&15, k=(lane>>4)*8+j)
  bf16x8 qf[4];
#pragma unroll
  for (int kc = 0; kc < 4; kc++)
    qf[kc] = *(const bf16x8*)(Qb + (size_t)(qw + lr) * RS + kc * 32 + lq * 8);

  f32x4 oacc[8] = {};
  float m_r[4], l_r[4];
#pragma unroll
  for (int r = 0; r < 4; r++) { m_r[r] = -INFINITY; l_r[r] = 0.f; }
  const float SC = 0.08838834764831845f * 1.4426950408889634f;  // D^-0.5 * log2(e)

  int krow = tid >> 4, kcol = (tid & 15) * 8;  // K staging
  int vc = tid & 127, vro = (tid >> 7) * 8;    // V staging

  int ntiles = qt + 1;
  for (int kt = 0; kt < ntiles; kt++) {
    int k0 = kt * 64;
    // stage K [64][128] (coalesced 16B loads)
#pragma unroll
    for (int i = 0; i < 4; i++)
      *(bf16x8*)&sK[(krow + i * 16) * LDKs + kcol] =
          *(const bf16x8*)(Kb + (size_t)(k0 + krow + i * 16) * RS + kcol);
    // stage V transposed: coalesced scalar global reads, vector LDS writes
#pragma unroll
    for (int i = 0; i < 4; i++) {
      int kr = vro + i * 16;
      bf16x8 vv;
#pragma unroll
      for (int j = 0; j < 8; j++) vv[j] = Vb[(size_t)(k0 + kr + j) * RS + vc];
      *(bf16x8*)&sVT[vc * LDV + kr] = vv;
    }
    __syncthreads();

    // S = Q K^T  (S: 16 q-rows x 64 k-cols, 4 col-fragments)
    float su[4][4];
#pragma unroll
    for (int nf = 0; nf < 4; nf++) {
      f32x4 sacc = {};
#pragma unroll
      for (int kc = 0; kc < 4; kc++) {
        bf16x8 kf = *(const bf16x8*)&sK[(nf * 16 + lr) * LDKs + kc * 32 + lq * 8];
        sacc = MFMA16x16x32(qf[kc], kf, sacc, 0, 0, 0);
      }
      int kg = k0 + nf * 16 + lr;
#pragma unroll
      for (int r = 0; r < 4; r++) {
        int qg = qw + lq * 4 + r;
        su[nf][r] = (kg <= qg) ? sacc[r] * SC : -INFINITY;
      }
    }
    // online softmax (log2 domain), rows live in 16-lane groups
    float rmax[4];
#pragma unroll
    for (int r = 0; r < 4; r++)
      rmax[r] = fmaxf(fmaxf(su[0][r], su[1][r]), fmaxf(su[2][r], su[3][r]));
#pragma unroll
    for (int mk = 1; mk < 16; mk <<= 1)
#pragma unroll
      for (int r = 0; r < 4; r++) rmax[r] = fmaxf(rmax[r], __shfl_xor(rmax[r], mk));
    float alpha[4], rsum[4];
#pragma unroll
    for (int r = 0; r < 4; r++) {
      float mn = fmaxf(m_r[r], rmax[r]);
      alpha[r] = exp2f(m_r[r] - mn);
      m_r[r] = mn;
      rsum[r] = 0.f;
    }
#pragma unroll
    for (int nf = 0; nf < 4; nf++)
#pragma unroll
      for (int r = 0; r < 4; r++) {
        float p = exp2f(su[nf][r] - m_r[r]);
        su[nf][r] = p;
        rsum[r] += p;
      }
#pragma unroll
    for (int mk = 1; mk < 16; mk <<= 1)
#pragma unroll
      for (int r = 0; r < 4; r++) rsum[r] += __shfl_xor(rsum[r], mk);
#pragma unroll
    for (int r = 0; r < 4; r++) l_r[r] = l_r[r] * alpha[r] + rsum[r];
#pragma unroll
    for (int of = 0; of < 8; of++)
#pragma unroll
      for (int r = 0; r < 4; r++) oacc[of][r] *= alpha[r];
    // write P (bf16) to per-wave LDS, then consume as A operand
#pragma unroll
    for (int nf = 0; nf < 4; nf++)
#pragma unroll
      for (int r = 0; r < 4; r++)
        sP[wid][(lq * 4 + r) * LDP + nf * 16 + lr] = (bf16_t)su[nf][r];
    asm volatile("s_waitcnt lgkmcnt(0)" ::: "memory");
    __builtin_amdgcn_sched_barrier(0);
    // O += P V
#pragma unroll
    for (int kc = 0; kc < 2; kc++) {
      bf16x8 pf = *(const bf16x8*)&sP[wid][lr * LDP + kc * 32 + lq * 8];
#pragma unroll
      for (int of = 0; of < 8; of++) {
        bf16x8 vf = *(const bf16x8*)&sVT[(of * 16 + lr) * LDV + kc * 32 + lq * 8];
        oacc[of] = MFMA16x16x32(pf, vf, oacc[of], 0, 0, 0);
      }
    }
    __syncthreads();
  }
  // epilogue: normalize and store bf16
#pragma unroll
  for (int r = 0; r < 4; r++) {
    float inv = 1.0f / l_r[r];
    size_t row = (size_t)b * 2048 + qw + lq * 4 + r;
#pragma unroll
    for (int of = 0; of < 8; of++)
      out[row * 2048 + h * 128 + of * 16 + lr] = (bf16_t)(oacc[of][r] * inv);
  }
}

extern "C" void kernel_launch(void* const* d_in, const int* in_sizes, int n_in,
                              void* d_out, int out_size, void* d_ws, size_t ws_size,
                              hipStream_t stream) {
  const float* x = (const float*)d_in[0];
  const float* Wq = (const float*)d_in[1];
  const float* Wk = (const float*)d_in[2];
  const float* Wv = (const float*)d_in[3];
  const float* Wp = (const float*)d_in[4];
  const float* bp = (const float*)d_in[5];
  float* out = (float*)d_out;

  bf16_t* ws = (bf16_t*)d_ws;
  // layout (bf16 elements): xb/attn_out 16.78M | qkv 25.17M | WqkvT 6.29M | WpT 4.19M
  bf16_t* xb = ws;                                   // 8192x2048 (attn out aliases this)
  bf16_t* qkv = ws + 16777216;                       // 8192x3072
  bf16_t* WqkvT = ws + 16777216 + 25165824;          // 3072x2048 (rows: q cols, k cols, v cols)
  bf16_t* WpT = WqkvT + 6291456;                     // 2048x2048

  k_f32_to_bf16<<<2048, 256, 0, stream>>>(x, xb, 16777216L);
  k_transpose_bf16<<<dim3(64, 64), 256, 0, stream>>>(Wq, WqkvT, 2048, 2048);
  k_transpose_bf16<<<dim3(16, 64), 256, 0, stream>>>(Wk, WqkvT + (size_t)2048 * 2048, 2048, 512);
  k_transpose_bf16<<<dim3(16, 64), 256, 0, stream>>>(Wv, WqkvT + (size_t)2560 * 2048, 2048, 512);
  k_transpose_bf16<<<dim3(64, 64), 256, 0, stream>>>(Wp, WpT, 2048, 2048);

  k_gemm_bt<false><<<64 * 24, 256, 0, stream>>>(xb, WqkvT, qkv, nullptr, nullptr, 8192, 3072, 2048);
  k_rope<<<40960, 256, 0, stream>>>(qkv);
  k_attn<<<dim3(32, 16, 4), 256, 0, stream>>>(qkv, xb);
  k_gemm_bt<true><<<64 * 16, 256, 0, stream>>>(xb, WpT, nullptr, out, bp, 8192, 2048, 2048);
}

// Round 2
// 520.803 us; speedup vs baseline: 1.3634x; 1.3634x over previous
//
#include <hip/hip_runtime.h>
#include <hip/hip_bf16.h>
#include <math.h>

typedef __bf16 bf16_t;
typedef __bf16 bf16x8 __attribute__((ext_vector_type(8)));
typedef __bf16 bf16x4 __attribute__((ext_vector_type(4)));
typedef float f32x4 __attribute__((ext_vector_type(4)));
typedef float f32x16 __attribute__((ext_vector_type(16)));
typedef unsigned int u32;

#define MFMA16 __builtin_amdgcn_mfma_f32_16x16x32_bf16
#define MFMA32 __builtin_amdgcn_mfma_f32_32x32x16_bf16

static __device__ __forceinline__ u32 pkbf(float a, float b) {
  union { bf16_t h[2]; u32 u; } z;
  z.h[0] = (bf16_t)a; z.h[1] = (bf16_t)b;
  return z.u;
}

// ---------------- x: f32 -> bf16 ----------------
__global__ void k_f32_to_bf16(const float* __restrict__ in, bf16_t* __restrict__ out, long n) {
  long i = ((long)blockIdx.x * blockDim.x + threadIdx.x) * 4;
  long stride = (long)gridDim.x * blockDim.x * 4;
  for (; i < n; i += stride) {
    const float4 v = *(const float4*)(in + i);
    bf16x4 o; o[0] = (bf16_t)v.x; o[1] = (bf16_t)v.y; o[2] = (bf16_t)v.z; o[3] = (bf16_t)v.w;
    *(bf16x4*)(out + i) = o;
  }
}

// ------------- W (KxN f32) -> WT (NxK bf16), LDS tile transpose -------------
__global__ void k_transpose_bf16(const float* __restrict__ W, bf16_t* __restrict__ WT,
                                 int K, int N) {
  __shared__ float tile[32][33];
  int n0 = blockIdx.x * 32, k0 = blockIdx.y * 32;
  int tx = threadIdx.x & 31, ty = threadIdx.x >> 5;
#pragma unroll
  for (int i = 0; i < 4; i++)
    tile[ty + i * 8][tx] = W[(size_t)(k0 + ty + i * 8) * N + n0 + tx];
  __syncthreads();
#pragma unroll
  for (int i = 0; i < 4; i++) {
    int n = ty + i * 8;
    WT[(size_t)(n0 + n) * K + k0 + tx] = (bf16_t)tile[tx][n];
  }
}

// ---------------- RoPE on q,k columns of qkv (in place) ----------------
__global__ void k_rope(bf16_t* __restrict__ qkv) {
  int idx = blockIdx.x * blockDim.x + threadIdx.x;
  if (idx >= 8192 * 1280) return;
  int r = idx / 1280, p = idx - r * 1280;
  int t = r & 2047;
  int i = p & 63;
  float theta = exp2f(-(float)i * 0.41524101186092029f);
  float f = (float)t * theta;
  float s, c;
  sincosf(f, &s, &c);
  bf16_t* a = qkv + (size_t)r * 3072 + p * 2;
  float e = (float)a[0], o = (float)a[1];
  a[0] = (bf16_t)(e * c - o * s);
  a[1] = (bf16_t)(e * s + o * c);
}

// ---------------- GEMM: C[MxN] = A[MxK] * BT[NxK]^T (+bias) ----------------
template <bool F32OUT>
__global__ __launch_bounds__(256, 2) void k_gemm_bt(
    const bf16_t* __restrict__ A, const bf16_t* __restrict__ BT,
    bf16_t* __restrict__ Cb, float* __restrict__ Cf,
    const float* __restrict__ bias, int M, int N, int K) {
  const int LDK = 72;
  __shared__ bf16_t sA[128 * 72];
  __shared__ bf16_t sB[128 * 72];
  int nbn = N >> 7;
  int bm = (int)blockIdx.x / nbn, bn = (int)blockIdx.x % nbn;
  int tid = threadIdx.x;
  int lane = tid & 63, wid = tid >> 6;
  int wm = (wid >> 1) << 6, wn = (wid & 1) << 6;
  int lr = lane & 15, lq = lane >> 4;
  f32x4 acc[4][4] = {};
  int srow = tid >> 3, scol = (tid & 7) * 8;
  const bf16_t* Ab = A + (size_t)(bm * 128 + srow) * K + scol;
  const bf16_t* Bb = BT + (size_t)(bn * 128 + srow) * K + scol;

  for (int k0 = 0; k0 < K; k0 += 64) {
#pragma unroll
    for (int i = 0; i < 4; i++) {
      *(bf16x8*)&sA[(srow + i * 32) * LDK + scol] = *(const bf16x8*)(Ab + (size_t)i * 32 * K + k0);
      *(bf16x8*)&sB[(srow + i * 32) * LDK + scol] = *(const bf16x8*)(Bb + (size_t)i * 32 * K + k0);
    }
    __syncthreads();
#pragma unroll
    for (int kc = 0; kc < 2; kc++) {
      bf16x8 af[4], bfr[4];
#pragma unroll
      for (int m = 0; m < 4; m++)
        af[m] = *(const bf16x8*)&sA[(wm + m * 16 + lr) * LDK + kc * 32 + lq * 8];
#pragma unroll
      for (int n = 0; n < 4; n++)
        bfr[n] = *(const bf16x8*)&sB[(wn + n * 16 + lr) * LDK + kc * 32 + lq * 8];
#pragma unroll
      for (int m = 0; m < 4; m++)
#pragma unroll
        for (int n = 0; n < 4; n++)
          acc[m][n] = MFMA16(af[m], bfr[n], acc[m][n], 0, 0, 0);
    }
    __syncthreads();
  }
#pragma unroll
  for (int m = 0; m < 4; m++) {
    int row0 = bm * 128 + wm + m * 16 + lq * 4;
#pragma unroll
    for (int n = 0; n < 4; n++) {
      int col = bn * 128 + wn + n * 16 + lr;
#pragma unroll
      for (int r = 0; r < 4; r++) {
        if constexpr (F32OUT)
          Cf[(size_t)(row0 + r) * N + col] = acc[m][n][r] + bias[col];
        else
          Cb[(size_t)(row0 + r) * N + col] = (bf16_t)acc[m][n][r];
      }
    }
  }
}

// ---------------- Flash attention v2 (causal, GQA), swapped-operand 32x32 ----------------
// grid: 1024 blocks = 16 q-tiles (interleaved heavy/light) x 16 heads x 4 batch.
// 256 thr = 4 waves x 32 q-rows. KVBLK=64. S^T = mfma(K,Q): lane-local softmax.
__global__ __launch_bounds__(256, 2) void k_attn(const bf16_t* __restrict__ qkv,
                                                 bf16_t* __restrict__ out) {
  __shared__ bf16_t sK[64 * 128];   // linear, XOR-swizzled: byte ^= (row&7)<<4
  __shared__ bf16_t sVT[128 * 72];  // V^T [d][k] + pad
  int bid = blockIdx.x;
  int g = bid >> 6;
  int qt = (g & 1) ? (g >> 1) : (15 - (g >> 1));  // heavy/light interleave
  int bh = bid & 63;
  int h = bh & 15, b = bh >> 4;
  int kvh = h >> 2;
  const size_t RS = 3072;
  const bf16_t* Qb = qkv + (size_t)b * 2048 * RS + h * 128;
  const bf16_t* Kb = qkv + (size_t)b * 2048 * RS + 2048 + kvh * 128;
  const bf16_t* Vb = Kb + 512;
  int q0 = qt * 128;
  int tid = threadIdx.x, lane = tid & 63, wid = tid >> 6;
  int l31 = lane & 31, hi = lane >> 5;
  int qw = q0 + wid * 32;

  // Q fragments (B operand): qf[dc][j] = Q[qw+l31][dc*16 + hi*8 + j]
  bf16x8 qf[8];
  {
    const bf16_t* qrow = Qb + (size_t)(qw + l31) * RS + hi * 8;
#pragma unroll
    for (int dc = 0; dc < 8; dc++)
      qf[dc] = *(const bf16x8*)(qrow + dc * 16);
  }

  f32x16 oT[4] = {};
  float m_r = -INFINITY, l_r = 0.f;
  const float SC = 0.08838834764831845f * 1.4426950408889634f;  // D^-0.5 * log2(e)

  int vc = tid & 127, vro = (tid >> 7) * 8;  // V staging

  int ntiles = 2 * qt + 2;
  for (int kt = 0; kt < ntiles; kt++) {
    int k0 = kt * 64;
    // --- stage K [64][128], XOR-swizzled, vectorized ---
#pragma unroll
    for (int ps = 0; ps < 4; ps++) {
      int idx = tid + ps * 256;
      int row = idx >> 4, seg = idx & 15;
      bf16x8 kv = *(const bf16x8*)(Kb + (size_t)(k0 + row) * RS + seg * 8);
      int off = row * 256 + ((seg * 16) ^ ((row & 7) << 4));
      *(bf16x8*)((char*)sK + off) = kv;
    }
    // --- stage V^T: coalesced scalar global column reads, vector LDS writes ---
#pragma unroll
    for (int i = 0; i < 4; i++) {
      int kr = vro + i * 16;
      bf16x8 vv;
#pragma unroll
      for (int j = 0; j < 8; j++) vv[j] = Vb[(size_t)(k0 + kr + j) * RS + vc];
      *(bf16x8*)&sVT[vc * 72 + kr] = vv;
    }
    __syncthreads();

    if (k0 <= qw + 31) {  // wave-uniform causal guard
      // --- S^T = K . Q^T : D[k][q], k=(r&3)+8*(r>>2)+4*hi (+32*nf), q=l31 ---
      f32x16 sa0 = {}, sa1 = {};
#pragma unroll
      for (int dc = 0; dc < 8; dc++) {
        int cb = (dc * 32 + hi * 16) ^ ((l31 & 7) << 4);
        bf16x8 kf0 = *(const bf16x8*)((const char*)sK + l31 * 256 + cb);
        bf16x8 kf1 = *(const bf16x8*)((const char*)sK + (32 + l31) * 256 + cb);
        sa0 = MFMA32(kf0, qf[dc], sa0, 0, 0, 0);
        sa1 = MFMA32(kf1, qf[dc], sa1, 0, 0, 0);
      }
      // --- mask + lane-local softmax (q = qw + l31) ---
      float p[2][16];
      int qg = qw + l31;
      float pm = -INFINITY;
#pragma unroll
      for (int nf = 0; nf < 2; nf++)
#pragma unroll
        for (int r = 0; r < 16; r++) {
          int kg = k0 + nf * 32 + (r & 3) + 8 * (r >> 2) + 4 * hi;
          float v = (kg <= qg) ? (nf ? sa1[r] : sa0[r]) * SC : -INFINITY;
          p[nf][r] = v;
          pm = fmaxf(pm, v);
        }
      pm = fmaxf(pm, __shfl_xor(pm, 32));
      bool skip = __all(pm <= m_r + 8.f);  // defer-max (T13)
      float mn = skip ? m_r : fmaxf(m_r, pm);
      float alpha = skip ? 1.f : exp2f(m_r - mn);
      m_r = mn;
      float rs = 0.f;
#pragma unroll
      for (int nf = 0; nf < 2; nf++)
#pragma unroll
        for (int r = 0; r < 16; r++) {
          float e = exp2f(p[nf][r] - m_r);
          p[nf][r] = e;
          rs += e;
        }
      rs += __shfl_xor(rs, 32);
      l_r = l_r * alpha + rs;
      if (!skip) {
#pragma unroll
        for (int c = 0; c < 4; c++)
#pragma unroll
          for (int r = 0; r < 16; r++) oT[c][r] *= alpha;
      }
      // --- P handoff in-register (cvt_pk + shfl_xor(32)) + PV: O^T += V^T P^T ---
#pragma unroll
      for (int nf = 0; nf < 2; nf++) {
        u32 Qk[4][2];
#pragma unroll
        for (int gg = 0; gg < 4; gg++) {
          Qk[gg][0] = pkbf(p[nf][4 * gg + 0], p[nf][4 * gg + 1]);
          Qk[gg][1] = pkbf(p[nf][4 * gg + 2], p[nf][4 * gg + 3]);
        }
#pragma unroll
        for (int kc = 0; kc < 2; kc++) {
          // partner sends the quad THIS lane needs: Qk[2kc + 1 - hi] evaluated
          // by lane^32 (hi'=1-hi) yields its Qk[2kc+hi].
          u32 x0 = __shfl_xor(Qk[2 * kc + 1 - hi][0], 32);
          u32 x1 = __shfl_xor(Qk[2 * kc + 1 - hi][1], 32);
          u32 o0 = Qk[2 * kc + hi][0], o1 = Qk[2 * kc + hi][1];
          union { u32 w[4]; bf16x8 v; } pf;
          pf.w[0] = hi ? x0 : o0;
          pf.w[1] = hi ? x1 : o1;
          pf.w[2] = hi ? o0 : x0;
          pf.w[3] = hi ? o1 : x1;
          int slot = nf * 2 + kc;
#pragma unroll
          for (int c = 0; c < 4; c++) {
            bf16x8 vf = *(const bf16x8*)&sVT[(c * 32 + l31) * 72 + slot * 16 + hi * 8];
            oT[c] = MFMA32(vf, pf.v, oT[c], 0, 0, 0);
          }
        }
      }
    }
    __syncthreads();
  }
  // --- epilogue: O^T store, lane-local l ---
  float inv = 1.f / l_r;
  size_t row = (size_t)b * 2048 + qw + l31;
#pragma unroll
  for (int c = 0; c < 4; c++)
#pragma unroll
    for (int rr = 0; rr < 4; rr++) {
      bf16x4 o4;
#pragma unroll
      for (int j = 0; j < 4; j++) o4[j] = (bf16_t)(oT[c][rr * 4 + j] * inv);
      *(bf16x4*)(out + row * 2048 + h * 128 + c * 32 + rr * 8 + hi * 4) = o4;
    }
}

extern "C" void kernel_launch(void* const* d_in, const int* in_sizes, int n_in,
                              void* d_out, int out_size, void* d_ws, size_t ws_size,
                              hipStream_t stream) {
  const float* x = (const float*)d_in[0];
  const float* Wq = (const float*)d_in[1];
  const float* Wk = (const float*)d_in[2];
  const float* Wv = (const float*)d_in[3];
  const float* Wp = (const float*)d_in[4];
  const float* bp = (const float*)d_in[5];
  float* out = (float*)d_out;

  bf16_t* ws = (bf16_t*)d_ws;
  bf16_t* xb = ws;                          // 8192x2048 (attn out aliases this)
  bf16_t* qkv = ws + 16777216;              // 8192x3072
  bf16_t* WqkvT = ws + 16777216 + 25165824; // 3072x2048
  bf16_t* WpT = WqkvT + 6291456;            // 2048x2048

  k_f32_to_bf16<<<2048, 256, 0, stream>>>(x, xb, 16777216L);
  k_transpose_bf16<<<dim3(64, 64), 256, 0, stream>>>(Wq, WqkvT, 2048, 2048);
  k_transpose_bf16<<<dim3(16, 64), 256, 0, stream>>>(Wk, WqkvT + (size_t)2048 * 2048, 2048, 512);
  k_transpose_bf16<<<dim3(16, 64), 256, 0, stream>>>(Wv, WqkvT + (size_t)2560 * 2048, 2048, 512);
  k_transpose_bf16<<<dim3(64, 64), 256, 0, stream>>>(Wp, WpT, 2048, 2048);

  k_gemm_bt<false><<<64 * 24, 256, 0, stream>>>(xb, WqkvT, qkv, nullptr, nullptr, 8192, 3072, 2048);
  k_rope<<<40960, 256, 0, stream>>>(qkv);
  k_attn<<<1024, 256, 0, stream>>>(qkv, xb);
  k_gemm_bt<true><<<64 * 16, 256, 0, stream>>>(xb, WpT, nullptr, out, bp, 8192, 2048, 2048);
}

// Round 3
// 428.046 us; speedup vs baseline: 1.6588x; 1.2167x over previous
//
#include <hip/hip_runtime.h>
#include <hip/hip_bf16.h>
#include <math.h>

typedef __bf16 bf16_t;
typedef __bf16 bf16x8 __attribute__((ext_vector_type(8)));
typedef __bf16 bf16x4 __attribute__((ext_vector_type(4)));
typedef float f32x4 __attribute__((ext_vector_type(4)));
typedef float f32x16 __attribute__((ext_vector_type(16)));
typedef unsigned int u32;

#define MFMA16 __builtin_amdgcn_mfma_f32_16x16x32_bf16
#define MFMA32 __builtin_amdgcn_mfma_f32_32x32x16_bf16

static __device__ __forceinline__ u32 pkbf(float a, float b) {
  union { bf16_t h[2]; u32 u; } z;
  z.h[0] = (bf16_t)a; z.h[1] = (bf16_t)b;
  return z.u;
}

// async global->LDS, 16B per lane, dest = wave-uniform base + lane*16
static __device__ __forceinline__ void gload16(const bf16_t* g, bf16_t* l) {
  __builtin_amdgcn_global_load_lds(
      (const __attribute__((address_space(1))) void*)g,
      (__attribute__((address_space(3))) void*)l, 16, 0, 0);
}

// ---------------- x: f32 -> bf16 ----------------
__global__ void k_f32_to_bf16(const float* __restrict__ in, bf16_t* __restrict__ out, long n) {
  long i = ((long)blockIdx.x * blockDim.x + threadIdx.x) * 4;
  long stride = (long)gridDim.x * blockDim.x * 4;
  for (; i < n; i += stride) {
    const float4 v = *(const float4*)(in + i);
    bf16x4 o; o[0] = (bf16_t)v.x; o[1] = (bf16_t)v.y; o[2] = (bf16_t)v.z; o[3] = (bf16_t)v.w;
    *(bf16x4*)(out + i) = o;
  }
}

// ------------- W (KxN f32) -> WT (NxK bf16), LDS tile transpose -------------
__global__ void k_transpose_bf16(const float* __restrict__ W, bf16_t* __restrict__ WT,
                                 int K, int N) {
  __shared__ float tile[32][33];
  int n0 = blockIdx.x * 32, k0 = blockIdx.y * 32;
  int tx = threadIdx.x & 31, ty = threadIdx.x >> 5;
#pragma unroll
  for (int i = 0; i < 4; i++)
    tile[ty + i * 8][tx] = W[(size_t)(k0 + ty + i * 8) * N + n0 + tx];
  __syncthreads();
#pragma unroll
  for (int i = 0; i < 4; i++) {
    int n = ty + i * 8;
    WT[(size_t)(n0 + n) * K + k0 + tx] = (bf16_t)tile[tx][n];
  }
}

// ---------------- RoPE on q,k columns of qkv (in place) ----------------
__global__ void k_rope(bf16_t* __restrict__ qkv) {
  int idx = blockIdx.x * blockDim.x + threadIdx.x;
  if (idx >= 8192 * 1280) return;
  int r = idx / 1280, p = idx - r * 1280;
  int t = r & 2047;
  int i = p & 63;
  float theta = exp2f(-(float)i * 0.41524101186092029f);
  float f = (float)t * theta;
  float s, c;
  sincosf(f, &s, &c);
  bf16_t* a = qkv + (size_t)r * 3072 + p * 2;
  float e = (float)a[0], o = (float)a[1];
  a[0] = (bf16_t)(e * c - o * s);
  a[1] = (bf16_t)(e * s + o * c);
}

// ---------------- GEMM (m97 structure): C[MxN] = A[MxK]*BT[NxK]^T (+bias) ----
// 128x128 tile, BK=64, 4 waves (2x2 of 64x64). Staging: global_load_lds x16B
// into LINEAR LDS [128][64] (wave-uniform dest + lane*16). XCD-swizzled grid.
template <bool F32OUT>
__global__ __launch_bounds__(256, 2) void k_gemm_bt(
    const bf16_t* __restrict__ A, const bf16_t* __restrict__ BT,
    bf16_t* __restrict__ Cb, float* __restrict__ Cf,
    const float* __restrict__ bias, int M, int N, int K, int nwg) {
  __shared__ bf16_t sA[128 * 64];
  __shared__ bf16_t sB[128 * 64];
  int nbn = N >> 7;
  // bijective XCD swizzle (nwg % 8 == 0 for all our grids)
  int orig = (int)blockIdx.x;
  int swz = (orig & 7) * (nwg >> 3) + (orig >> 3);
  int bm = swz / nbn, bn = swz % nbn;
  int tid = threadIdx.x;
  int lane = tid & 63, wid = tid >> 6;
  int wm = (wid >> 1) << 6, wn = (wid & 1) << 6;
  int lr = lane & 15, lq = lane >> 4;
  f32x4 acc[4][4] = {};

  // staging addresses: wave wid covers rows [wid*32, wid*32+32), 4 issues of 8 rows
  int srow = wid * 32 + (lane >> 3);
  int scol = (lane & 7) * 8;
  const bf16_t* Ag = A + (size_t)(bm * 128 + srow) * K + scol;
  const bf16_t* Bg = BT + (size_t)(bn * 128 + srow) * K + scol;
  bf16_t* Al = &sA[(wid * 32) * 64];
  bf16_t* Bl = &sB[(wid * 32) * 64];

  for (int k0 = 0; k0 < K; k0 += 64) {
#pragma unroll
    for (int i = 0; i < 4; i++) {
      gload16(Ag + (size_t)i * 8 * K + k0, Al + i * 8 * 64);
      gload16(Bg + (size_t)i * 8 * K + k0, Bl + i * 8 * 64);
    }
    __syncthreads();  // drains vmcnt (gload_lds) + lgkm
#pragma unroll
    for (int kc = 0; kc < 2; kc++) {
      bf16x8 af[4], bfr[4];
#pragma unroll
      for (int m = 0; m < 4; m++)
        af[m] = *(const bf16x8*)&sA[(wm + m * 16 + lr) * 64 + kc * 32 + lq * 8];
#pragma unroll
      for (int n = 0; n < 4; n++)
        bfr[n] = *(const bf16x8*)&sB[(wn + n * 16 + lr) * 64 + kc * 32 + lq * 8];
#pragma unroll
      for (int m = 0; m < 4; m++)
#pragma unroll
        for (int n = 0; n < 4; n++)
          acc[m][n] = MFMA16(af[m], bfr[n], acc[m][n], 0, 0, 0);
    }
    __syncthreads();
  }
#pragma unroll
  for (int m = 0; m < 4; m++) {
    int row0 = bm * 128 + wm + m * 16 + lq * 4;
#pragma unroll
    for (int n = 0; n < 4; n++) {
      int col = bn * 128 + wn + n * 16 + lr;
#pragma unroll
      for (int r = 0; r < 4; r++) {
        if constexpr (F32OUT)
          Cf[(size_t)(row0 + r) * N + col] = acc[m][n][r] + bias[col];
        else
          Cb[(size_t)(row0 + r) * N + col] = (bf16_t)acc[m][n][r];
      }
    }
  }
}

// ---------------- Flash attention v2 (causal, GQA), swapped-operand 32x32 ----------------
// grid: 1024 blocks = 16 q-tiles (interleaved heavy/light) x 16 heads x 4 batch.
// 256 thr = 4 waves x 32 q-rows. KVBLK=64. S^T = mfma(K,Q): lane-local softmax.
__global__ __launch_bounds__(256, 2) void k_attn(const bf16_t* __restrict__ qkv,
                                                 bf16_t* __restrict__ out) {
  __shared__ bf16_t sK[64 * 128];   // linear, XOR-swizzled: byte ^= (row&7)<<4
  __shared__ bf16_t sVT[128 * 72];  // V^T [d][k] + pad
  int bid = blockIdx.x;
  int g = bid >> 6;
  int qt = (g & 1) ? (g >> 1) : (15 - (g >> 1));  // heavy/light interleave
  int bh = bid & 63;
  int h = bh & 15, b = bh >> 4;
  int kvh = h >> 2;
  const size_t RS = 3072;
  const bf16_t* Qb = qkv + (size_t)b * 2048 * RS + h * 128;
  const bf16_t* Kb = qkv + (size_t)b * 2048 * RS + 2048 + kvh * 128;
  const bf16_t* Vb = Kb + 512;
  int q0 = qt * 128;
  int tid = threadIdx.x, lane = tid & 63, wid = tid >> 6;
  int l31 = lane & 31, hi = lane >> 5;
  int qw = q0 + wid * 32;

  // Q fragments (B operand): qf[dc][j] = Q[qw+l31][dc*16 + hi*8 + j]
  bf16x8 qf[8];
  {
    const bf16_t* qrow = Qb + (size_t)(qw + l31) * RS + hi * 8;
#pragma unroll
    for (int dc = 0; dc < 8; dc++)
      qf[dc] = *(const bf16x8*)(qrow + dc * 16);
  }

  f32x16 oT[4] = {};
  float m_r = -INFINITY, l_r = 0.f;
  const float SC = 0.08838834764831845f * 1.4426950408889634f;  // D^-0.5 * log2(e)

  int vc = tid & 127, vro = (tid >> 7) * 8;  // V staging

  int ntiles = 2 * qt + 2;
  for (int kt = 0; kt < ntiles; kt++) {
    int k0 = kt * 64;
    // --- stage K [64][128], XOR-swizzled, vectorized ---
#pragma unroll
    for (int ps = 0; ps < 4; ps++) {
      int idx = tid + ps * 256;
      int row = idx >> 4, seg = idx & 15;
      bf16x8 kv = *(const bf16x8*)(Kb + (size_t)(k0 + row) * RS + seg * 8);
      int off = row * 256 + ((seg * 16) ^ ((row & 7) << 4));
      *(bf16x8*)((char*)sK + off) = kv;
    }
    // --- stage V^T: coalesced scalar global column reads, vector LDS writes ---
#pragma unroll
    for (int i = 0; i < 4; i++) {
      int kr = vro + i * 16;
      bf16x8 vv;
#pragma unroll
      for (int j = 0; j < 8; j++) vv[j] = Vb[(size_t)(k0 + kr + j) * RS + vc];
      *(bf16x8*)&sVT[vc * 72 + kr] = vv;
    }
    __syncthreads();

    if (k0 <= qw + 31) {  // wave-uniform causal guard
      // --- S^T = K . Q^T : D[k][q], k=(r&3)+8*(r>>2)+4*hi (+32*nf), q=l31 ---
      f32x16 sa0 = {}, sa1 = {};
#pragma unroll
      for (int dc = 0; dc < 8; dc++) {
        int cb = (dc * 32 + hi * 16) ^ ((l31 & 7) << 4);
        bf16x8 kf0 = *(const bf16x8*)((const char*)sK + l31 * 256 + cb);
        bf16x8 kf1 = *(const bf16x8*)((const char*)sK + (32 + l31) * 256 + cb);
        sa0 = MFMA32(kf0, qf[dc], sa0, 0, 0, 0);
        sa1 = MFMA32(kf1, qf[dc], sa1, 0, 0, 0);
      }
      // --- mask + lane-local softmax (q = qw + l31) ---
      float p[2][16];
      int qg = qw + l31;
      float pm = -INFINITY;
#pragma unroll
      for (int nf = 0; nf < 2; nf++)
#pragma unroll
        for (int r = 0; r < 16; r++) {
          int kg = k0 + nf * 32 + (r & 3) + 8 * (r >> 2) + 4 * hi;
          float v = (kg <= qg) ? (nf ? sa1[r] : sa0[r]) * SC : -INFINITY;
          p[nf][r] = v;
          pm = fmaxf(pm, v);
        }
      pm = fmaxf(pm, __shfl_xor(pm, 32));
      bool skip = __all(pm <= m_r + 8.f);  // defer-max (T13)
      float mn = skip ? m_r : fmaxf(m_r, pm);
      float alpha = skip ? 1.f : exp2f(m_r - mn);
      m_r = mn;
      float rs = 0.f;
#pragma unroll
      for (int nf = 0; nf < 2; nf++)
#pragma unroll
        for (int r = 0; r < 16; r++) {
          float e = exp2f(p[nf][r] - m_r);
          p[nf][r] = e;
          rs += e;
        }
      rs += __shfl_xor(rs, 32);
      l_r = l_r * alpha + rs;
      if (!skip) {
#pragma unroll
        for (int c = 0; c < 4; c++)
#pragma unroll
          for (int r = 0; r < 16; r++) oT[c][r] *= alpha;
      }
      // --- P handoff in-register (cvt_pk + shfl_xor(32)) + PV: O^T += V^T P^T ---
#pragma unroll
      for (int nf = 0; nf < 2; nf++) {
        u32 Qk[4][2];
#pragma unroll
        for (int gg = 0; gg < 4; gg++) {
          Qk[gg][0] = pkbf(p[nf][4 * gg + 0], p[nf][4 * gg + 1]);
          Qk[gg][1] = pkbf(p[nf][4 * gg + 2], p[nf][4 * gg + 3]);
        }
#pragma unroll
        for (int kc = 0; kc < 2; kc++) {
          u32 x0 = __shfl_xor(Qk[2 * kc + 1 - hi][0], 32);
          u32 x1 = __shfl_xor(Qk[2 * kc + 1 - hi][1], 32);
          u32 o0 = Qk[2 * kc + hi][0], o1 = Qk[2 * kc + hi][1];
          union { u32 w[4]; bf16x8 v; } pf;
          pf.w[0] = hi ? x0 : o0;
          pf.w[1] = hi ? x1 : o1;
          pf.w[2] = hi ? o0 : x0;
          pf.w[3] = hi ? o1 : x1;
          int slot = nf * 2 + kc;
#pragma unroll
          for (int c = 0; c < 4; c++) {
            bf16x8 vf = *(const bf16x8*)&sVT[(c * 32 + l31) * 72 + slot * 16 + hi * 8];
            oT[c] = MFMA32(vf, pf.v, oT[c], 0, 0, 0);
          }
        }
      }
    }
    __syncthreads();
  }
  // --- epilogue: O^T store, lane-local l ---
  float inv = 1.f / l_r;
  size_t row = (size_t)b * 2048 + qw + l31;
#pragma unroll
  for (int c = 0; c < 4; c++)
#pragma unroll
    for (int rr = 0; rr < 4; rr++) {
      bf16x4 o4;
#pragma unroll
      for (int j = 0; j < 4; j++) o4[j] = (bf16_t)(oT[c][rr * 4 + j] * inv);
      *(bf16x4*)(out + row * 2048 + h * 128 + c * 32 + rr * 8 + hi * 4) = o4;
    }
}

extern "C" void kernel_launch(void* const* d_in, const int* in_sizes, int n_in,
                              void* d_out, int out_size, void* d_ws, size_t ws_size,
                              hipStream_t stream) {
  const float* x = (const float*)d_in[0];
  const float* Wq = (const float*)d_in[1];
  const float* Wk = (const float*)d_in[2];
  const float* Wv = (const float*)d_in[3];
  const float* Wp = (const float*)d_in[4];
  const float* bp = (const float*)d_in[5];
  float* out = (float*)d_out;

  bf16_t* ws = (bf16_t*)d_ws;
  bf16_t* xb = ws;                          // 8192x2048 (attn out aliases this)
  bf16_t* qkv = ws + 16777216;              // 8192x3072
  bf16_t* WqkvT = ws + 16777216 + 25165824; // 3072x2048
  bf16_t* WpT = WqkvT + 6291456;            // 2048x2048

  k_f32_to_bf16<<<2048, 256, 0, stream>>>(x, xb, 16777216L);
  k_transpose_bf16<<<dim3(64, 64), 256, 0, stream>>>(Wq, WqkvT, 2048, 2048);
  k_transpose_bf16<<<dim3(16, 64), 256, 0, stream>>>(Wk, WqkvT + (size_t)2048 * 2048, 2048, 512);
  k_transpose_bf16<<<dim3(16, 64), 256, 0, stream>>>(Wv, WqkvT + (size_t)2560 * 2048, 2048, 512);
  k_transpose_bf16<<<dim3(64, 64), 256, 0, stream>>>(Wp, WpT, 2048, 2048);

  k_gemm_bt<false><<<64 * 24, 256, 0, stream>>>(xb, WqkvT, qkv, nullptr, nullptr, 8192, 3072, 2048, 64 * 24);
  k_rope<<<40960, 256, 0, stream>>>(qkv);
  k_attn<<<1024, 256, 0, stream>>>(qkv, xb);
  k_gemm_bt<true><<<64 * 16, 256, 0, stream>>>(xb, WpT, nullptr, out, bp, 8192, 2048, 2048, 64 * 16);
}